// Round 12
// baseline (1539.708 us; speedup 1.0000x reference)
//
#include <hip/hip_runtime.h>

#define T_STEPS 512
#define B_ROWS  64
#define F_DIM   256
#define U_DIM   1024
#define G3      3072   // 3*U
#define PACC_BYTES (2 * 12 * 64 * 16)     // parity x (4acc x 3waves) x 64 lanes x 16B
#define LDS_BYTES (PACC_BYTES + 512)

// h exchange: 5-slot rotation of [4 rowtile groups][64 tiles][512 B].
// Sentinel protocol (r8/r10/r11, proven): data IS the signal; tiles
// re-poisoned with bf16-NaN 3 slots ahead; ordering via vmcnt drains + the
// per-step dump barrier (poison now on wave3 — see proof in comments).
#define NSLOT  5
#define TILE_B 512
#define GRP_B  (64 * TILE_B)      // 32 KB per rowtile group
#define SLOT_B (4 * GRP_B)        // 128 KB per slot
#define SENT   0x7FC17FC1u        // 2x bf16 NaN — h is always finite

typedef __bf16 bf16x8 __attribute__((ext_vector_type(8)));
typedef float  f32x4  __attribute__((ext_vector_type(4)));
typedef unsigned int u32x2 __attribute__((ext_vector_type(2)));
typedef unsigned int u32x4 __attribute__((ext_vector_type(4)));

__device__ __forceinline__ float sigmoidf_(float v) {
    return 1.f / (1.f + __expf(-v));
}
__device__ __forceinline__ float tanhf_(float v) {
    float e2 = __expf(2.f * v);
    return 1.f - 2.f / (e2 + 1.f);
}

// ---------------------------------------------------------------------------
// Transpose + cvt recurrent kernel: [1024][3072] f32 -> [3072][1024] bf16
// ---------------------------------------------------------------------------
__global__ __launch_bounds__(256) void transpose_cvt_kernel(
    const float* __restrict__ src, __bf16* __restrict__ dst, int Kdim)
{
    __shared__ float tile[32][33];
    const int n0 = blockIdx.x * 32;
    const int k0 = blockIdx.y * 32;
    const int j  = threadIdx.x & 31;
    const int i0 = threadIdx.x >> 5;
#pragma unroll
    for (int s = 0; s < 4; ++s) {
        int i = i0 * 4 + s;
        tile[i][j] = src[(size_t)(k0 + i) * G3 + n0 + j];
    }
    __syncthreads();
#pragma unroll
    for (int s = 0; s < 4; ++s) {
        int i = i0 * 4 + s;
        dst[(size_t)(n0 + i) * Kdim + k0 + j] = (__bf16)tile[j][i];
    }
}

// ---------------------------------------------------------------------------
// Init: hidden f32 -> bf16 tiles in slot 0; slots 1..4 = sentinel.
// ---------------------------------------------------------------------------
__global__ __launch_bounds__(256) void init_kernel(
    const float* __restrict__ hidden, char* __restrict__ rot)
{
    const int i = blockIdx.x * 256 + threadIdx.x;   // 0..65535
    const int row = i >> 10, u = i & 1023;
    const int rt = row >> 4, rl = row & 15, c = u >> 4, ul = u & 15;
    *(__bf16*)(rot + rt * GRP_B + c * TILE_B + ((rl << 4) + ul) * 2) =
        (__bf16)hidden[i];
    unsigned* s = (unsigned*)(rot + SLOT_B);        // slots 1..4
    s[2 * i]     = SENT;
    s[2 * i + 1] = SENT;
}

// ---------------------------------------------------------------------------
// Persistent GRU. Grid = 256 blocks x 256 threads (4 waves, 1 block/CU).
// Block (rt=bid>>6: 16 rows, c=bid&63: 16 u's).
// WAVE ROLES:
//   wave 0 (driver): NO X work. Per step: 8 asm h-loads -> 4 out-stores
//     (newest, excluded from fast poll) -> poll vmcnt(4) fast-shot /
//     vmcnt(0) retries -> H k-slice [0,256) -> sync -> reduce(+X partials
//     from LDS) -> gates -> pack -> publish (sole trailing store).
//   waves 1-3: H k-slice [256w,256w+256) + X k-chunks (3/3/2 of 32) ->
//     poll vmcnt(0) -> dump 4 partial accs to LDS -> sync. Wave 3 poisons
//     slot (t+3)%5 after sync (constant store; drained by its next poll,
//     which precedes sync(t+1), which precedes wave0's publish(t+1) -> the
//     r8 ordering proof holds through the barrier).
// ALL B-fragments live in registers. LDS = partial-acc exchange + pack only.
// ---------------------------------------------------------------------------
__global__ __launch_bounds__(256, 1) void gru_persistent(
    const float* __restrict__ x,       // [64][512][256] f32
    const float* __restrict__ hidden,  // [64][1024] f32
    const float* __restrict__ bias,    // [2][3072] f32
    const float* __restrict__ kern,    // [256][3072] f32 (input kernel)
    const __bf16* __restrict__ Rt,     // [3072][1024] bf16
    char* __restrict__ rot,            // NSLOT * SLOT_B bytes
    float* __restrict__ out)           // [64][512][1024] f32 (+ state tail)
{
    extern __shared__ char lds_raw[];
    float*  pacc  = (float*)lds_raw;
    __bf16* hpack = (__bf16*)(lds_raw + PACC_BYTES); // [16][16]

    const int tid  = threadIdx.x;
    const int lane = tid & 63;
    const int wv   = tid >> 6;        // 0..3
    const int rc   = lane & 15;
    const int kg   = lane >> 4;
    const int bid  = blockIdx.x;
    const int c    = bid & 63;
    const int rt   = bid >> 6;
    const int u    = (c << 4) + rc;
    const int row0 = rt << 4;

    if (wv == 0) __builtin_amdgcn_s_setprio(1);

    const int gu0 = u;
    const int gu1 = U_DIM + u;
    const int gu2 = 2 * U_DIM + u;

    // ---- hoist H B-fragments into registers (all waves) ----
    bf16x8 whz[8], whr[8], whh[8];
#pragma unroll
    for (int ki = 0; ki < 8; ++ki) {
        const int col = (wv << 8) + (ki << 5) + (kg << 3);
        whz[ki] = *(const bf16x8*)(Rt + (size_t)gu0 * U_DIM + col);
        whr[ki] = *(const bf16x8*)(Rt + (size_t)gu1 * U_DIM + col);
        whh[ki] = *(const bf16x8*)(Rt + (size_t)gu2 * U_DIM + col);
    }

    // ---- X B-fragments: waves 1-3 only (k-chunks 3/3/2 of 32) ----
    const int xnck = (wv == 1 || wv == 2) ? 3 : (wv == 3 ? 2 : 0);
    const int xoff = (wv == 2) ? 96 : (wv == 3 ? 192 : 0);
    bf16x8 wxz[3], wxr[3], wxh[3];
#pragma unroll
    for (int ci = 0; ci < 3; ++ci) {
        if (ci < xnck) {
#pragma unroll
            for (int e = 0; e < 8; ++e) {
                const int k = xoff + ci * 32 + (kg << 3) + e;
                wxz[ci][e] = (__bf16)kern[(size_t)k * G3 + gu0];
                wxr[ci][e] = (__bf16)kern[(size_t)k * G3 + gu1];
                wxh[ci][e] = (__bf16)kern[(size_t)k * G3 + gu2];
            }
        }
    }

    // ---- wave0-only invariants ----
    float hprev[4] = {0.f, 0.f, 0.f, 0.f};
    if (wv == 0) {
#pragma unroll
        for (int j = 0; j < 4; ++j)
            hprev[j] = hidden[(size_t)(row0 + (kg << 2) + j) * U_DIM + u];
    }
    const float bz_ = bias[u]             + bias[G3 + u];
    const float br_ = bias[U_DIM + u]     + bias[G3 + U_DIM + u];
    const float bhx = bias[2 * U_DIM + u];
    const float bhr = bias[G3 + 2 * U_DIM + u];

    const float* xbase = x + (size_t)(row0 + rc) * (T_STEPS * F_DIM) + (kg << 3);

    const int grp_b = rt * GRP_B;
    const int lan_b = (wv << 13) + ((kg >> 1) << 9) + (rc << 5) + ((kg & 1) << 4);
    const int my_b  = grp_b + c * TILE_B + (lane << 3);

    int slot_r = 0, slot_w = 1, slot_p = 3;
    const u32x2 sentv = { SENT, SENT };

    for (int t = 0; t < T_STEPS; ++t) {
        f32x4 accZ  = {0.f, 0.f, 0.f, 0.f};
        f32x4 accR  = {0.f, 0.f, 0.f, 0.f};
        f32x4 accHX = {0.f, 0.f, 0.f, 0.f};  // stays 0 on wave0
        f32x4 accHR = {0.f, 0.f, 0.f, 0.f};
        const int p = t & 1;

        // ---- spec-issue my 8 h(t-1) fragment loads (slot t%5) ----
        const char* hb = rot + slot_r * SLOT_B + grp_b + lan_b;
        bf16x8 hfrag[8];
#define HL(ki, m, lit)                                                         \
        asm volatile("global_load_dwordx4 %0, %1, off offset:" lit " sc0 sc1"  \
                     : "=v"(hfrag[ki]) : "v"(hb + (m) * 4096) : "memory");
#define HLOADS()                                                               \
        HL(0,0,"0") HL(1,0,"1024") HL(2,0,"2048") HL(3,0,"3072")               \
        HL(4,1,"0") HL(5,1,"1024") HL(6,1,"2048") HL(7,1,"3072")
        HLOADS()

        if (wv == 0) {
            // ---- out[t-1] stores: issued AFTER the loads -> they are the
            //      4 NEWEST VM ops and survive the vmcnt(4) fast-shot ----
            if (t > 0) {
#pragma unroll
                for (int j = 0; j < 4; ++j) {
                    const int row = row0 + (kg << 2) + j;
                    out[((size_t)row * T_STEPS + (t - 1)) * U_DIM + u] = hprev[j];
                }
            }
            // ---- driver poll: fast-shot vmcnt(4) (retires publish + 8
            //      h-loads, oldest-first; leaves out-stores in flight) ----
            bool first = (t > 0);
            for (;;) {
                if (first) {
                    asm volatile("s_waitcnt vmcnt(4)" ::: "memory");
                    first = false;
                } else {
                    asm volatile("s_waitcnt vmcnt(0)" ::: "memory");
                }
                __builtin_amdgcn_sched_barrier(0);
                int ok = 1;
#pragma unroll
                for (int ki = 0; ki < 8; ++ki) {
                    const u32x4 w = __builtin_bit_cast(u32x4, hfrag[ki]);
                    ok &= (w[0] != SENT) & (w[2] != SENT);
                }
                if (__all(ok)) break;
                HLOADS()
            }
        } else {
            // ---- X phase: my k-chunks (B-frags from registers) ----
            const float* ap = xbase + t * F_DIM;
#pragma unroll
            for (int ci = 0; ci < 3; ++ci) {
                if (ci < xnck) {
                    const int k0 = xoff + ci * 32;
                    const float4 a0 = *(const float4*)(ap + k0);
                    const float4 a1 = *(const float4*)(ap + k0 + 4);
                    bf16x8 af;
                    af[0] = (__bf16)a0.x; af[1] = (__bf16)a0.y;
                    af[2] = (__bf16)a0.z; af[3] = (__bf16)a0.w;
                    af[4] = (__bf16)a1.x; af[5] = (__bf16)a1.y;
                    af[6] = (__bf16)a1.z; af[7] = (__bf16)a1.w;
                    accZ  = __builtin_amdgcn_mfma_f32_16x16x32_bf16(af, wxz[ci], accZ,  0, 0, 0);
                    accR  = __builtin_amdgcn_mfma_f32_16x16x32_bf16(af, wxr[ci], accR,  0, 0, 0);
                    accHX = __builtin_amdgcn_mfma_f32_16x16x32_bf16(af, wxh[ci], accHX, 0, 0, 0);
                }
            }
            // ---- poll (no stores of mine in flight worth keeping) ----
            for (;;) {
                asm volatile("s_waitcnt vmcnt(0)" ::: "memory");
                __builtin_amdgcn_sched_barrier(0);
                int ok = 1;
#pragma unroll
                for (int ki = 0; ki < 8; ++ki) {
                    const u32x4 w = __builtin_bit_cast(u32x4, hfrag[ki]);
                    ok &= (w[0] != SENT) & (w[2] != SENT);
                }
                if (__all(ok)) break;
                HLOADS()
            }
        }
#undef HLOADS
#undef HL

        // ---- H phase: 24 pure-register MFMAs (my 256-k slice) ----
#pragma unroll
        for (int ki = 0; ki < 8; ++ki) {
            const bf16x8 af = hfrag[ki];
            accZ  = __builtin_amdgcn_mfma_f32_16x16x32_bf16(af, whz[ki], accZ,  0, 0, 0);
            accR  = __builtin_amdgcn_mfma_f32_16x16x32_bf16(af, whr[ki], accR,  0, 0, 0);
            accHR = __builtin_amdgcn_mfma_f32_16x16x32_bf16(af, whh[ki], accHR, 0, 0, 0);
        }

        // ---- waves 1-3: dump partials (parity-buffered) ----
        if (wv != 0) {
            const int w1 = wv - 1;
            *(f32x4*)&pacc[(((p * 12) + 0 * 3 + w1) * 64 + lane) * 4] = accZ;
            *(f32x4*)&pacc[(((p * 12) + 1 * 3 + w1) * 64 + lane) * 4] = accR;
            *(f32x4*)&pacc[(((p * 12) + 2 * 3 + w1) * 64 + lane) * 4] = accHX;
            *(f32x4*)&pacc[(((p * 12) + 3 * 3 + w1) * 64 + lane) * 4] = accHR;
        }
        __syncthreads();

        // ---- wave 3: poison slot (t+3)%5 (constant store, any wave OK;
        //      drained by wave3's next poll before sync(t+1) < publish(t+1))
        if (wv == 3) {
            asm volatile("global_store_dwordx2 %0, %1, off sc0 sc1"
                         :: "v"(rot + slot_p * SLOT_B + my_b), "v"(sentv) : "memory");
        }

        // ---- wave 0: reduce (X comes in via partials), gates, publish ----
        if (wv == 0) {
#pragma unroll
            for (int w1 = 0; w1 < 3; ++w1) {
                accZ  += *(const f32x4*)&pacc[(((p * 12) + 0 * 3 + w1) * 64 + lane) * 4];
                accR  += *(const f32x4*)&pacc[(((p * 12) + 1 * 3 + w1) * 64 + lane) * 4];
                accHX += *(const f32x4*)&pacc[(((p * 12) + 2 * 3 + w1) * 64 + lane) * 4];
                accHR += *(const f32x4*)&pacc[(((p * 12) + 3 * 3 + w1) * 64 + lane) * 4];
            }
#pragma unroll
            for (int j = 0; j < 4; ++j) {
                const float z  = sigmoidf_(accZ[j] + bz_);
                const float r  = sigmoidf_(accR[j] + br_);
                const float hh = tanhf_(accHX[j] + bhx + r * (accHR[j] + bhr));
                hprev[j] = z * hprev[j] + (1.f - z) * hh;
            }
#pragma unroll
            for (int j = 0; j < 4; ++j)
                hpack[(((kg << 2) + j) << 4) + rc] = (__bf16)hprev[j];
            const u32x2 hv = *(const u32x2*)(hpack + ((lane >> 2) << 4) + ((lane & 3) << 2));
            asm volatile("global_store_dwordx2 %0, %1, off sc0 sc1"
                         :: "v"(rot + slot_w * SLOT_B + my_b), "v"(hv) : "memory");
        }

        if (++slot_r == NSLOT) slot_r = 0;
        if (++slot_w == NSLOT) slot_w = 0;
        if (++slot_p == NSLOT) slot_p = 0;
    }

    // ---- final: out[T-1] + state tail (wave 0) ----
    if (wv == 0) {
#pragma unroll
        for (int j = 0; j < 4; ++j) {
            const int row = row0 + (kg << 2) + j;
            out[((size_t)row * T_STEPS + (T_STEPS - 1)) * U_DIM + u] = hprev[j];
            out[(size_t)B_ROWS * T_STEPS * U_DIM + (size_t)row * U_DIM + u] = hprev[j];
        }
    }
}

extern "C" void kernel_launch(void* const* d_in, const int* in_sizes, int n_in,
                              void* d_out, int out_size, void* d_ws, size_t ws_size,
                              hipStream_t stream)
{
    const float* x      = (const float*)d_in[0];  // [64,512,256]
    const float* hidden = (const float*)d_in[1];  // [64,1024]
    const float* kernel = (const float*)d_in[2];  // [256,3072]
    const float* rker   = (const float*)d_in[3];  // [1024,3072]
    const float* bias   = (const float*)d_in[4];  // [2,3072]
    float* out = (float*)d_out;

    const size_t rt_el = (size_t)G3 * U_DIM;
    __bf16* Rt = (__bf16*)d_ws;                   // 6.29 MB
    char* rot  = (char*)(Rt + rt_el);             // 640 KB (5 slots)

    hipLaunchKernelGGL(transpose_cvt_kernel, dim3(G3 / 32, U_DIM / 32), dim3(256),
                       0, stream, rker, Rt, U_DIM);
    hipLaunchKernelGGL(init_kernel, dim3(256), dim3(256), 0, stream, hidden, rot);

    void* kx = (void*)&x;  void* kh = (void*)&hidden; void* kb = (void*)&bias;
    void* kk = (void*)&kernel; void* kR = (void*)&Rt;
    void* kr = (void*)&rot; void* ko = (void*)&out;
    void* args[7] = { kx, kh, kb, kk, kR, kr, ko };

    auto kfn = gru_persistent;
    (void)hipFuncSetAttribute((const void*)kfn,
                              hipFuncAttributeMaxDynamicSharedMemorySize, LDS_BYTES);
    hipError_t ce = hipLaunchCooperativeKernel(kfn, dim3(256), dim3(256), args,
                                               LDS_BYTES, stream);
    if (ce != hipSuccess) {
        // Fallback: plain launch. 1 block/CU on 256 CUs -> all blocks
        // co-resident; the spin protocol remains deadlock-free.
        hipLaunchKernelGGL(gru_persistent, dim3(256), dim3(256), LDS_BYTES, stream,
                           x, hidden, bias, kernel, Rt, rot, out);
    }
}

// Round 13
// 1536.847 us; speedup vs baseline: 1.0019x; 1.0019x over previous
//
#include <hip/hip_runtime.h>

#define T_STEPS 512
#define B_ROWS  64
#define F_DIM   256
#define U_DIM   1024
#define G3      3072   // 3*U
#define PACC_BYTES (2 * 16 * 64 * 16)     // parity x (4acc x 4waves) x 64 lanes x 16B
#define LDS_BYTES (PACC_BYTES + 512)      // + 4 x 128B pack strips

// h exchange: 5-slot rotation of [4 rowtile groups][64 tiles][512 B].
// Sentinel protocol (r8/r10/r11, proven): data IS the signal; tiles
// re-poisoned with bf16-NaN 3 slots ahead; ordering via each wave's own
// per-step vmcnt(0) drain (now per-wave for its own quarter-tile).
#define NSLOT  5
#define TILE_B 512
#define GRP_B  (64 * TILE_B)      // 32 KB per rowtile group
#define SLOT_B (4 * GRP_B)        // 128 KB per slot
#define SENT   0x7FC17FC1u        // 2x bf16 NaN — h is always finite

typedef __bf16 bf16x8 __attribute__((ext_vector_type(8)));
typedef float  f32x4  __attribute__((ext_vector_type(4)));
typedef unsigned int u32x2 __attribute__((ext_vector_type(2)));
typedef unsigned int u32x4 __attribute__((ext_vector_type(4)));

__device__ __forceinline__ float sigmoidf_(float v) {
    return 1.f / (1.f + __expf(-v));
}
__device__ __forceinline__ float tanhf_(float v) {
    float e2 = __expf(2.f * v);
    return 1.f - 2.f / (e2 + 1.f);
}

// ---------------------------------------------------------------------------
// Transpose + cvt recurrent kernel: [1024][3072] f32 -> [3072][1024] bf16
// ---------------------------------------------------------------------------
__global__ __launch_bounds__(256) void transpose_cvt_kernel(
    const float* __restrict__ src, __bf16* __restrict__ dst, int Kdim)
{
    __shared__ float tile[32][33];
    const int n0 = blockIdx.x * 32;
    const int k0 = blockIdx.y * 32;
    const int j  = threadIdx.x & 31;
    const int i0 = threadIdx.x >> 5;
#pragma unroll
    for (int s = 0; s < 4; ++s) {
        int i = i0 * 4 + s;
        tile[i][j] = src[(size_t)(k0 + i) * G3 + n0 + j];
    }
    __syncthreads();
#pragma unroll
    for (int s = 0; s < 4; ++s) {
        int i = i0 * 4 + s;
        dst[(size_t)(n0 + i) * Kdim + k0 + j] = (__bf16)tile[j][i];
    }
}

// ---------------------------------------------------------------------------
// Init: hidden f32 -> bf16 tiles in slot 0; slots 1..4 = sentinel.
// ---------------------------------------------------------------------------
__global__ __launch_bounds__(256) void init_kernel(
    const float* __restrict__ hidden, char* __restrict__ rot)
{
    const int i = blockIdx.x * 256 + threadIdx.x;   // 0..65535
    const int row = i >> 10, u = i & 1023;
    const int rt = row >> 4, rl = row & 15, c = u >> 4, ul = u & 15;
    *(__bf16*)(rot + rt * GRP_B + c * TILE_B + ((rl << 4) + ul) * 2) =
        (__bf16)hidden[i];
    unsigned* s = (unsigned*)(rot + SLOT_B);        // slots 1..4
    s[2 * i]     = SENT;
    s[2 * i + 1] = SENT;
}

// ---------------------------------------------------------------------------
// Persistent GRU. Grid = 256 blocks x 256 threads (4 waves, 1 block/CU).
// Block (rt=bid>>6: 16 rows, c=bid&63: 16 u's). UNIFORM waves (r11 skeleton):
// wave w: H k-slice [256w,256w+256) (regs), X k-slice [64w,64w+64) (regs).
// Per step: spec-issue 8 h-loads (slot t%5) -> X-GEMM -> out[t-1] store
// (1/lane, own rows) -> sentinel poll vmcnt(0) -> H-GEMM -> ALL waves dump
// 4 partial accs to LDS -> sync -> DISTRIBUTED EPILOGUE: wave w owns rows
// [4w,4w+4): per-lane scalar reduce over 4 source waves, 1 gate set, pack
// into per-wave LDS strip, lanes 0-15 publish own 128B quarter (8B/lane) +
// poison quarter of slot (t+3)%5. Reduce order sv=0..3 == r11 bit-exact.
// ---------------------------------------------------------------------------
__global__ __launch_bounds__(256, 1) void gru_persistent(
    const float* __restrict__ x,       // [64][512][256] f32
    const float* __restrict__ hidden,  // [64][1024] f32
    const float* __restrict__ bias,    // [2][3072] f32
    const float* __restrict__ kern,    // [256][3072] f32 (input kernel)
    const __bf16* __restrict__ Rt,     // [3072][1024] bf16
    char* __restrict__ rot,            // NSLOT * SLOT_B bytes
    float* __restrict__ out)           // [64][512][1024] f32 (+ state tail)
{
    extern __shared__ char lds_raw[];
    float*  pacc  = (float*)lds_raw;                 // [2][4sv][4acc][64][4]
    __bf16* hpack = (__bf16*)(lds_raw + PACC_BYTES); // 4 x [4][16] strips

    const int tid  = threadIdx.x;
    const int lane = tid & 63;
    const int wv   = tid >> 6;        // 0..3
    const int rc   = lane & 15;
    const int kg   = lane >> 4;
    const int bid  = blockIdx.x;
    const int c    = bid & 63;
    const int rt   = bid >> 6;
    const int u    = (c << 4) + rc;
    const int row0 = rt << 4;

    const int gu0 = u;
    const int gu1 = U_DIM + u;
    const int gu2 = 2 * U_DIM + u;
    const int xk0 = wv << 6;          // X k-slice base

    // ---- hoist ALL B-fragments into registers (once) ----
    bf16x8 whz[8], whr[8], whh[8];    // H-weights: contiguous 16B from Rt
#pragma unroll
    for (int ki = 0; ki < 8; ++ki) {
        const int col = (wv << 8) + (ki << 5) + (kg << 3);
        whz[ki] = *(const bf16x8*)(Rt + (size_t)gu0 * U_DIM + col);
        whr[ki] = *(const bf16x8*)(Rt + (size_t)gu1 * U_DIM + col);
        whh[ki] = *(const bf16x8*)(Rt + (size_t)gu2 * U_DIM + col);
    }
    bf16x8 wxz[2], wxr[2], wxh[2];    // X-weights: scattered one-time f32
#pragma unroll
    for (int fx = 0; fx < 2; ++fx) {
#pragma unroll
        for (int e = 0; e < 8; ++e) {
            const int k = xk0 + fx * 32 + (kg << 3) + e;
            wxz[fx][e] = (__bf16)kern[(size_t)k * G3 + gu0];
            wxr[fx][e] = (__bf16)kern[(size_t)k * G3 + gu1];
            wxh[fx][e] = (__bf16)kern[(size_t)k * G3 + gu2];
        }
    }

    // ---- epilogue ownership: wave wv owns rows [4wv, 4wv+4) ----
    const int myrow = row0 + (wv << 2) + (lane >> 4);   // this lane's row
    const int myu   = (c << 4) + (lane & 15);           // this lane's u (==u)
    float hprev_s = hidden[(size_t)myrow * U_DIM + myu];

    const float bz_ = bias[myu]             + bias[G3 + myu];
    const float br_ = bias[U_DIM + myu]     + bias[G3 + U_DIM + myu];
    const float bhx = bias[2 * U_DIM + myu];
    const float bhr = bias[G3 + 2 * U_DIM + myu];

    const float* xbase = x + (size_t)(row0 + rc) * (T_STEPS * F_DIM)
                           + xk0 + (kg << 3);

    const int grp_b = rt * GRP_B;
    // consumer: this wave's fragment base within the group
    const int lan_b = (wv << 13) + ((kg >> 1) << 9) + (rc << 5) + ((kg & 1) << 4);
    // producer: this wave's 128B quarter of the block's tile (lanes 0-15)
    const int my_b  = grp_b + c * TILE_B + (wv << 7) + ((lane & 15) << 3);
    __bf16* mypack = hpack + (wv << 6);                 // 64 bf16 strip

    int slot_r = 0, slot_w = 1, slot_p = 3;
    const u32x2 sentv = { SENT, SENT };

    for (int t = 0; t < T_STEPS; ++t) {
        f32x4 accZ  = {0.f, 0.f, 0.f, 0.f};
        f32x4 accR  = {0.f, 0.f, 0.f, 0.f};
        f32x4 accHX = {0.f, 0.f, 0.f, 0.f};
        f32x4 accHR = {0.f, 0.f, 0.f, 0.f};
        const int p = t & 1;

        // ---- spec-issue my 8 h(t-1) fragment loads (slot t%5) ----
        const char* hb = rot + slot_r * SLOT_B + grp_b + lan_b;
        bf16x8 hfrag[8];
#define HL(ki, m, lit)                                                         \
        asm volatile("global_load_dwordx4 %0, %1, off offset:" lit " sc0 sc1"  \
                     : "=v"(hfrag[ki]) : "v"(hb + (m) * 4096) : "memory");
#define HLOADS()                                                               \
        HL(0,0,"0") HL(1,0,"1024") HL(2,0,"2048") HL(3,0,"3072")               \
        HL(4,1,"0") HL(5,1,"1024") HL(6,1,"2048") HL(7,1,"3072")
        HLOADS()

        // ---- X phase: my 64-k slice, B-frags from registers ----
        const float* ap = xbase + t * F_DIM;
#pragma unroll
        for (int fx = 0; fx < 2; ++fx) {
            const float4 a0 = *(const float4*)(ap + fx * 32);
            const float4 a1 = *(const float4*)(ap + fx * 32 + 4);
            bf16x8 af;
            af[0] = (__bf16)a0.x; af[1] = (__bf16)a0.y;
            af[2] = (__bf16)a0.z; af[3] = (__bf16)a0.w;
            af[4] = (__bf16)a1.x; af[5] = (__bf16)a1.y;
            af[6] = (__bf16)a1.z; af[7] = (__bf16)a1.w;
            accZ  = __builtin_amdgcn_mfma_f32_16x16x32_bf16(af, wxz[fx], accZ,  0, 0, 0);
            accR  = __builtin_amdgcn_mfma_f32_16x16x32_bf16(af, wxr[fx], accR,  0, 0, 0);
            accHX = __builtin_amdgcn_mfma_f32_16x16x32_bf16(af, wxh[fx], accHX, 0, 0, 0);
        }

        // ---- out[t-1]: 1 f32/lane, own row (64B contiguous per 16 lanes) ----
        if (t > 0)
            out[((size_t)myrow * T_STEPS + (t - 1)) * U_DIM + myu] = hprev_s;

        // ---- sentinel poll: my 8 fragments must be real data ----
        for (;;) {
            asm volatile("s_waitcnt vmcnt(0)" ::: "memory");
            __builtin_amdgcn_sched_barrier(0);
            int ok = 1;
#pragma unroll
            for (int ki = 0; ki < 8; ++ki) {
                const u32x4 w = __builtin_bit_cast(u32x4, hfrag[ki]);
                ok &= (w[0] != SENT) & (w[2] != SENT);
            }
            if (__all(ok)) break;
            HLOADS()
        }
#undef HLOADS
#undef HL

        // ---- H phase: 24 pure-register MFMAs ----
#pragma unroll
        for (int ki = 0; ki < 8; ++ki) {
            const bf16x8 af = hfrag[ki];
            accZ  = __builtin_amdgcn_mfma_f32_16x16x32_bf16(af, whz[ki], accZ,  0, 0, 0);
            accR  = __builtin_amdgcn_mfma_f32_16x16x32_bf16(af, whr[ki], accR,  0, 0, 0);
            accHR = __builtin_amdgcn_mfma_f32_16x16x32_bf16(af, whh[ki], accHR, 0, 0, 0);
        }

        // ---- ALL waves dump partials (parity-buffered) ----
        {
            float* dbase = pacc + ((p * 4 + wv) * 4) * 256;
            *(f32x4*)&dbase[(0 * 64 + lane) * 4] = accZ;
            *(f32x4*)&dbase[(1 * 64 + lane) * 4] = accR;
            *(f32x4*)&dbase[(2 * 64 + lane) * 4] = accHX;
            *(f32x4*)&dbase[(3 * 64 + lane) * 4] = accHR;
        }
        __syncthreads();

        // ---- distributed epilogue: wave wv owns rows [4wv,4wv+4) ----
        {
            const int src = (wv << 4) + (lane & 15);    // source lane
            const int jj  = lane >> 4;                  // source acc element
            float vZ = 0.f, vR = 0.f, vHX = 0.f, vHR = 0.f;
#pragma unroll
            for (int sv = 0; sv < 4; ++sv) {
                const float* rb = pacc + ((p * 4 + sv) * 4) * 256;
                vZ  += rb[(0 * 64 + src) * 4 + jj];
                vR  += rb[(1 * 64 + src) * 4 + jj];
                vHX += rb[(2 * 64 + src) * 4 + jj];
                vHR += rb[(3 * 64 + src) * 4 + jj];
            }
            const float z  = sigmoidf_(vZ + bz_);
            const float r  = sigmoidf_(vR + br_);
            const float hh = tanhf_(vHX + bhx + r * (vHR + bhr));
            hprev_s = z * hprev_s + (1.f - z) * hh;

            // pack into my wave's 128B strip: [row-in-quarter][u] bf16
            mypack[((lane >> 4) << 4) + (lane & 15)] = (__bf16)hprev_s;
            // lanes 0-15: publish my quarter (8B each) + poison quarter
            if (lane < 16) {
                const u32x2 hv = *(const u32x2*)(mypack + (lane << 2));
                asm volatile("global_store_dwordx2 %0, %1, off sc0 sc1"
                             :: "v"(rot + slot_w * SLOT_B + my_b), "v"(hv) : "memory");
                asm volatile("global_store_dwordx2 %0, %1, off sc0 sc1"
                             :: "v"(rot + slot_p * SLOT_B + my_b), "v"(sentv) : "memory");
            }
        }

        if (++slot_r == NSLOT) slot_r = 0;
        if (++slot_w == NSLOT) slot_w = 0;
        if (++slot_p == NSLOT) slot_p = 0;
    }

    // ---- final: out[T-1] + state tail (own element) ----
    out[((size_t)myrow * T_STEPS + (T_STEPS - 1)) * U_DIM + myu] = hprev_s;
    out[(size_t)B_ROWS * T_STEPS * U_DIM + (size_t)myrow * U_DIM + myu] = hprev_s;
}

extern "C" void kernel_launch(void* const* d_in, const int* in_sizes, int n_in,
                              void* d_out, int out_size, void* d_ws, size_t ws_size,
                              hipStream_t stream)
{
    const float* x      = (const float*)d_in[0];  // [64,512,256]
    const float* hidden = (const float*)d_in[1];  // [64,1024]
    const float* kernel = (const float*)d_in[2];  // [256,3072]
    const float* rker   = (const float*)d_in[3];  // [1024,3072]
    const float* bias   = (const float*)d_in[4];  // [2,3072]
    float* out = (float*)d_out;

    const size_t rt_el = (size_t)G3 * U_DIM;
    __bf16* Rt = (__bf16*)d_ws;                   // 6.29 MB
    char* rot  = (char*)(Rt + rt_el);             // 640 KB (5 slots)

    hipLaunchKernelGGL(transpose_cvt_kernel, dim3(G3 / 32, U_DIM / 32), dim3(256),
                       0, stream, rker, Rt, U_DIM);
    hipLaunchKernelGGL(init_kernel, dim3(256), dim3(256), 0, stream, hidden, rot);

    void* kx = (void*)&x;  void* kh = (void*)&hidden; void* kb = (void*)&bias;
    void* kk = (void*)&kernel; void* kR = (void*)&Rt;
    void* kr = (void*)&rot; void* ko = (void*)&out;
    void* args[7] = { kx, kh, kb, kk, kR, kr, ko };

    auto kfn = gru_persistent;
    (void)hipFuncSetAttribute((const void*)kfn,
                              hipFuncAttributeMaxDynamicSharedMemorySize, LDS_BYTES);
    hipError_t ce = hipLaunchCooperativeKernel(kfn, dim3(256), dim3(256), args,
                                               LDS_BYTES, stream);
    if (ce != hipSuccess) {
        // Fallback: plain launch. 1 block/CU on 256 CUs -> all blocks
        // co-resident; the spin protocol remains deadlock-free.
        hipLaunchKernelGGL(gru_persistent, dim3(256), dim3(256), LDS_BYTES, stream,
                           x, hidden, bias, kernel, Rt, rot, out);
    }
}

// Round 16
// 1388.086 us; speedup vs baseline: 1.1092x; 1.1072x over previous
//
#include <hip/hip_runtime.h>

#define T_STEPS 512
#define B_ROWS  64
#define F_DIM   256
#define U_DIM   1024
#define G3      3072   // 3*U
#define PACC_BYTES (2 * 12 * 64 * 16)     // parity x (4acc x 3waves) x 64 lanes x 16B
#define LDS_BYTES (PACC_BYTES + 512)

// h exchange: 5-slot rotation of [4 rowtile groups][64 tiles][512 B].
// Sentinel protocol (r8/r10/r11, proven): data IS the signal; tiles re-poisoned
// with bf16-NaN 3 slots ahead; ordering via each step's poll vmcnt(0) drain.
// System scope (sc0 sc1) on all protocol ops — sc1-only deadlocks (r14):
// the publish store stays in the producer XCD's non-coherent L2.
// Single-set poll with FULL vmcnt(0) per check — counted-vmcnt ping-pong
// (r14/r15) hangs; the drain-everything poll is self-synchronizing.
#define NSLOT  5
#define TILE_B 512
#define GRP_B  (64 * TILE_B)      // 32 KB per rowtile group
#define SLOT_B (4 * GRP_B)        // 128 KB per slot
#define SENT   0x7FC17FC1u        // 2x bf16 NaN — h is always finite

typedef __bf16 bf16x8 __attribute__((ext_vector_type(8)));
typedef float  f32x4  __attribute__((ext_vector_type(4)));
typedef unsigned int u32x2 __attribute__((ext_vector_type(2)));
typedef unsigned int u32x4 __attribute__((ext_vector_type(4)));

__device__ __forceinline__ float sigmoidf_(float v) {
    return 1.f / (1.f + __expf(-v));
}
__device__ __forceinline__ float tanhf_(float v) {
    float e2 = __expf(2.f * v);
    return 1.f - 2.f / (e2 + 1.f);
}

// ---------------------------------------------------------------------------
// Transpose + cvt recurrent kernel: [1024][3072] f32 -> [3072][1024] bf16
// ---------------------------------------------------------------------------
__global__ __launch_bounds__(256) void transpose_cvt_kernel(
    const float* __restrict__ src, __bf16* __restrict__ dst, int Kdim)
{
    __shared__ float tile[32][33];
    const int n0 = blockIdx.x * 32;
    const int k0 = blockIdx.y * 32;
    const int j  = threadIdx.x & 31;
    const int i0 = threadIdx.x >> 5;
#pragma unroll
    for (int s = 0; s < 4; ++s) {
        int i = i0 * 4 + s;
        tile[i][j] = src[(size_t)(k0 + i) * G3 + n0 + j];
    }
    __syncthreads();
#pragma unroll
    for (int s = 0; s < 4; ++s) {
        int i = i0 * 4 + s;
        dst[(size_t)(n0 + i) * Kdim + k0 + j] = (__bf16)tile[j][i];
    }
}

// ---------------------------------------------------------------------------
// Init: hidden f32 -> bf16 tiles in slot 0; slots 1..4 = sentinel.
// ---------------------------------------------------------------------------
__global__ __launch_bounds__(256) void init_kernel(
    const float* __restrict__ hidden, char* __restrict__ rot)
{
    const int i = blockIdx.x * 256 + threadIdx.x;   // 0..65535
    const int row = i >> 10, u = i & 1023;
    const int rt = row >> 4, rl = row & 15, c = u >> 4, ul = u & 15;
    *(__bf16*)(rot + rt * GRP_B + c * TILE_B + ((rl << 4) + ul) * 2) =
        (__bf16)hidden[i];
    unsigned* s = (unsigned*)(rot + SLOT_B);        // slots 1..4
    s[2 * i]     = SENT;
    s[2 * i + 1] = SENT;
}

// ---------------------------------------------------------------------------
// Persistent GRU. Grid = 256 blocks x 256 threads (4 waves, 1 block/CU,
// 1 wave/SIMD -> ~450 VGPR budget/wave). Block (rt=bid>>6, c=bid&63).
// K-SPLIT: wave w owns H k-slice [256w,256w+256) and X k-slice [64w,64w+64).
// ALL B-fragments (30 x bf16x8 = 120 VGPR) live in REGISTERS — zero LDS
// reads in the step loop except the partial-acc exchange.
// Per step: spec-issue 8 h-loads (slot t%5) -> X-GEMM (regs) -> wave0 out[t-1]
// -> sentinel poll -> H-GEMM (regs) -> dump partials -> sync -> wave0:
// reduce + gates + pack + ONE 8B publish store/lane + poison (t+3)%5.
// ---------------------------------------------------------------------------
__global__ __launch_bounds__(256, 1) void gru_persistent(
    const float* __restrict__ x,       // [64][512][256] f32
    const float* __restrict__ hidden,  // [64][1024] f32
    const float* __restrict__ bias,    // [2][3072] f32
    const float* __restrict__ kern,    // [256][3072] f32 (input kernel)
    const __bf16* __restrict__ Rt,     // [3072][1024] bf16
    char* __restrict__ rot,            // NSLOT * SLOT_B bytes
    float* __restrict__ out)           // [64][512][1024] f32 (+ state tail)
{
    extern __shared__ char lds_raw[];
    float*  pacc  = (float*)lds_raw;
    __bf16* hpack = (__bf16*)(lds_raw + PACC_BYTES); // [16][16]

    const int tid  = threadIdx.x;
    const int lane = tid & 63;
    const int wv   = tid >> 6;        // 0..3
    const int rc   = lane & 15;
    const int kg   = lane >> 4;
    const int bid  = blockIdx.x;
    const int c    = bid & 63;
    const int rt   = bid >> 6;
    const int u    = (c << 4) + rc;
    const int row0 = rt << 4;

    if (wv == 0) __builtin_amdgcn_s_setprio(1);

    const int gu0 = u;
    const int gu1 = U_DIM + u;
    const int gu2 = 2 * U_DIM + u;
    const int xk0 = wv << 6;          // X k-slice base

    // ---- hoist ALL B-fragments into registers (once) ----
    bf16x8 whz[8], whr[8], whh[8];    // H-weights: contiguous 16B from Rt
#pragma unroll
    for (int ki = 0; ki < 8; ++ki) {
        const int col = (wv << 8) + (ki << 5) + (kg << 3);
        whz[ki] = *(const bf16x8*)(Rt + (size_t)gu0 * U_DIM + col);
        whr[ki] = *(const bf16x8*)(Rt + (size_t)gu1 * U_DIM + col);
        whh[ki] = *(const bf16x8*)(Rt + (size_t)gu2 * U_DIM + col);
    }
    bf16x8 wxz[2], wxr[2], wxh[2];    // X-weights: scattered one-time f32
#pragma unroll
    for (int fx = 0; fx < 2; ++fx) {
#pragma unroll
        for (int e = 0; e < 8; ++e) {
            const int k = xk0 + fx * 32 + (kg << 3) + e;
            wxz[fx][e] = (__bf16)kern[(size_t)k * G3 + gu0];
            wxr[fx][e] = (__bf16)kern[(size_t)k * G3 + gu1];
            wxh[fx][e] = (__bf16)kern[(size_t)k * G3 + gu2];
        }
    }

    // ---- per-thread invariants ----
    float hprev[4];
#pragma unroll
    for (int j = 0; j < 4; ++j)
        hprev[j] = hidden[(size_t)(row0 + (kg << 2) + j) * U_DIM + u];

    const float bz_ = bias[u]             + bias[G3 + u];
    const float br_ = bias[U_DIM + u]     + bias[G3 + U_DIM + u];
    const float bhx = bias[2 * U_DIM + u];
    const float bhr = bias[G3 + 2 * U_DIM + u];

    const float* xbase = x + (size_t)(row0 + rc) * (T_STEPS * F_DIM)
                           + xk0 + (kg << 3);

    const int grp_b = rt * GRP_B;
    const int lan_b = (wv << 13) + ((kg >> 1) << 9) + (rc << 5) + ((kg & 1) << 4);
    const int my_b  = grp_b + c * TILE_B + (lane << 3);

    int slot_r = 0, slot_w = 1, slot_p = 3;
    const u32x2 sentv = { SENT, SENT };

    for (int t = 0; t < T_STEPS; ++t) {
        f32x4 accZ  = {0.f, 0.f, 0.f, 0.f};
        f32x4 accR  = {0.f, 0.f, 0.f, 0.f};
        f32x4 accHX = {0.f, 0.f, 0.f, 0.f};
        f32x4 accHR = {0.f, 0.f, 0.f, 0.f};
        const int p = t & 1;

        // ---- spec-issue my 8 h(t-1) fragment loads (slot t%5) ----
        const char* hb = rot + slot_r * SLOT_B + grp_b + lan_b;
        bf16x8 hfrag[8];
#define HL(ki, m, lit)                                                         \
        asm volatile("global_load_dwordx4 %0, %1, off offset:" lit " sc0 sc1"  \
                     : "=v"(hfrag[ki]) : "v"(hb + (m) * 4096) : "memory");
#define HLOADS()                                                               \
        HL(0,0,"0") HL(1,0,"1024") HL(2,0,"2048") HL(3,0,"3072")               \
        HL(4,1,"0") HL(5,1,"1024") HL(6,1,"2048") HL(7,1,"3072")
        HLOADS()

        // ---- X phase: my 64-k slice, B-frags from registers ----
        const float* ap = xbase + t * F_DIM;
#pragma unroll
        for (int fx = 0; fx < 2; ++fx) {
            const float4 a0 = *(const float4*)(ap + fx * 32);
            const float4 a1 = *(const float4*)(ap + fx * 32 + 4);
            bf16x8 af;
            af[0] = (__bf16)a0.x; af[1] = (__bf16)a0.y;
            af[2] = (__bf16)a0.z; af[3] = (__bf16)a0.w;
            af[4] = (__bf16)a1.x; af[5] = (__bf16)a1.y;
            af[6] = (__bf16)a1.z; af[7] = (__bf16)a1.w;
            accZ  = __builtin_amdgcn_mfma_f32_16x16x32_bf16(af, wxz[fx], accZ,  0, 0, 0);
            accR  = __builtin_amdgcn_mfma_f32_16x16x32_bf16(af, wxr[fx], accR,  0, 0, 0);
            accHX = __builtin_amdgcn_mfma_f32_16x16x32_bf16(af, wxh[fx], accHX, 0, 0, 0);
        }

        // ---- wave0: store out[t-1] (fills remaining RTT) ----
        if (wv == 0 && t > 0) {
#pragma unroll
            for (int j = 0; j < 4; ++j) {
                const int row = row0 + (kg << 2) + j;
                out[((size_t)row * T_STEPS + (t - 1)) * U_DIM + u] = hprev[j];
            }
        }

        // ---- sentinel poll: my 8 fragments must be real data ----
        for (;;) {
            asm volatile("s_waitcnt vmcnt(0)" ::: "memory");
            __builtin_amdgcn_sched_barrier(0);
            int ok = 1;
#pragma unroll
            for (int ki = 0; ki < 8; ++ki) {
                const u32x4 w = __builtin_bit_cast(u32x4, hfrag[ki]);
                ok &= (w[0] != SENT) & (w[2] != SENT);
            }
            if (__all(ok)) break;
            HLOADS()
        }
#undef HLOADS
#undef HL

        // ---- H phase: 24 pure-register MFMAs ----
#pragma unroll
        for (int ki = 0; ki < 8; ++ki) {
            const bf16x8 af = hfrag[ki];
            accZ  = __builtin_amdgcn_mfma_f32_16x16x32_bf16(af, whz[ki], accZ,  0, 0, 0);
            accR  = __builtin_amdgcn_mfma_f32_16x16x32_bf16(af, whr[ki], accR,  0, 0, 0);
            accHR = __builtin_amdgcn_mfma_f32_16x16x32_bf16(af, whh[ki], accHR, 0, 0, 0);
        }

        // ---- waves 1-3: dump partials (parity-buffered) ----
        if (wv != 0) {
            const int w1 = wv - 1;
            *(f32x4*)&pacc[(((p * 12) + 0 * 3 + w1) * 64 + lane) * 4] = accZ;
            *(f32x4*)&pacc[(((p * 12) + 1 * 3 + w1) * 64 + lane) * 4] = accR;
            *(f32x4*)&pacc[(((p * 12) + 2 * 3 + w1) * 64 + lane) * 4] = accHX;
            *(f32x4*)&pacc[(((p * 12) + 3 * 3 + w1) * 64 + lane) * 4] = accHR;
        }
        __syncthreads();

        // ---- wave 0: reduce, gates, publish (single 8B store), poison ----
        if (wv == 0) {
#pragma unroll
            for (int w1 = 0; w1 < 3; ++w1) {
                accZ  += *(const f32x4*)&pacc[(((p * 12) + 0 * 3 + w1) * 64 + lane) * 4];
                accR  += *(const f32x4*)&pacc[(((p * 12) + 1 * 3 + w1) * 64 + lane) * 4];
                accHX += *(const f32x4*)&pacc[(((p * 12) + 2 * 3 + w1) * 64 + lane) * 4];
                accHR += *(const f32x4*)&pacc[(((p * 12) + 3 * 3 + w1) * 64 + lane) * 4];
            }
#pragma unroll
            for (int j = 0; j < 4; ++j) {
                const float z  = sigmoidf_(accZ[j] + bz_);
                const float r  = sigmoidf_(accR[j] + br_);
                const float hh = tanhf_(accHX[j] + bhx + r * (accHR[j] + bhr));
                hprev[j] = z * hprev[j] + (1.f - z) * hh;
            }
#pragma unroll
            for (int j = 0; j < 4; ++j)
                hpack[(((kg << 2) + j) << 4) + rc] = (__bf16)hprev[j];
            const u32x2 hv = *(const u32x2*)(hpack + ((lane >> 2) << 4) + ((lane & 3) << 2));
            asm volatile("global_store_dwordx2 %0, %1, off sc0 sc1"
                         :: "v"(rot + slot_w * SLOT_B + my_b), "v"(hv) : "memory");
            asm volatile("global_store_dwordx2 %0, %1, off sc0 sc1"
                         :: "v"(rot + slot_p * SLOT_B + my_b), "v"(sentv) : "memory");
        }

        if (++slot_r == NSLOT) slot_r = 0;
        if (++slot_w == NSLOT) slot_w = 0;
        if (++slot_p == NSLOT) slot_p = 0;
    }

    // ---- final: out[T-1] + state tail (wave 0) ----
    if (wv == 0) {
#pragma unroll
        for (int j = 0; j < 4; ++j) {
            const int row = row0 + (kg << 2) + j;
            out[((size_t)row * T_STEPS + (T_STEPS - 1)) * U_DIM + u] = hprev[j];
            out[(size_t)B_ROWS * T_STEPS * U_DIM + (size_t)row * U_DIM + u] = hprev[j];
        }
    }
}

extern "C" void kernel_launch(void* const* d_in, const int* in_sizes, int n_in,
                              void* d_out, int out_size, void* d_ws, size_t ws_size,
                              hipStream_t stream)
{
    const float* x      = (const float*)d_in[0];  // [64,512,256]
    const float* hidden = (const float*)d_in[1];  // [64,1024]
    const float* kernel = (const float*)d_in[2];  // [256,3072]
    const float* rker   = (const float*)d_in[3];  // [1024,3072]
    const float* bias   = (const float*)d_in[4];  // [2,3072]
    float* out = (float*)d_out;

    const size_t rt_el = (size_t)G3 * U_DIM;
    __bf16* Rt = (__bf16*)d_ws;                   // 6.29 MB
    char* rot  = (char*)(Rt + rt_el);             // 640 KB (5 slots)

    hipLaunchKernelGGL(transpose_cvt_kernel, dim3(G3 / 32, U_DIM / 32), dim3(256),
                       0, stream, rker, Rt, U_DIM);
    hipLaunchKernelGGL(init_kernel, dim3(256), dim3(256), 0, stream, hidden, rot);

    void* kx = (void*)&x;  void* kh = (void*)&hidden; void* kb = (void*)&bias;
    void* kk = (void*)&kernel; void* kR = (void*)&Rt;
    void* kr = (void*)&rot; void* ko = (void*)&out;
    void* args[7] = { kx, kh, kb, kk, kR, kr, ko };

    auto kfn = gru_persistent;
    (void)hipFuncSetAttribute((const void*)kfn,
                              hipFuncAttributeMaxDynamicSharedMemorySize, LDS_BYTES);
    hipError_t ce = hipLaunchCooperativeKernel(kfn, dim3(256), dim3(256), args,
                                               LDS_BYTES, stream);
    if (ce != hipSuccess) {
        // Fallback: plain launch. 1 block/CU on 256 CUs -> all blocks
        // co-resident; the spin protocol remains deadlock-free.
        hipLaunchKernelGGL(gru_persistent, dim3(256), dim3(256), LDS_BYTES, stream,
                           x, hidden, bias, kernel, Rt, rot, out);
    }
}